// Round 2
// baseline (7447.987 us; speedup 1.0000x reference)
//
#include <hip/hip_runtime.h>
#include <math.h>

// Problem constants
#define N_B     2
#define T_SEQ   2048
#define D_MODEL 1024
#define N_HEADS 16
#define D_HEAD  64
#define TOPK_N  64
#define CAP     256   // max kept entries per row (64 + tie slack)

// laplace(x) = 0.5*(1+erf((x-mu)*sqrt(2/pi))), mu=sqrt(.5)
#define LAP_MU  0.70710678118654752440
#define LAP_INV 0.79788456080286535588

// decode a monotone-u64 key back to the double it represents
__device__ __forceinline__ double key2d(unsigned long long k) {
  unsigned long long b = (k & 0x8000000000000000ull) ? (k & 0x7fffffffffffffffull) : ~k;
  return __longlong_as_double((long long)b);
}

// ---------------------------------------------------------------------------
// fp32 GEMM: out = A @ W^T + bias (used for V-projection and out-projection).
// ---------------------------------------------------------------------------
__global__ __launch_bounds__(256)
void gemm_nt(const float* __restrict__ A, const float* __restrict__ W,
             const float* __restrict__ bias, float* __restrict__ out,
             int M, int N, int Kd, int head_layout)
{
  __shared__ float As[64][33];
  __shared__ float Ws[64][33];
  const int t = threadIdx.x;
  const int row0 = blockIdx.x * 64, col0 = blockIdx.y * 64;
  const int ty = t >> 4, tx = t & 15;
  float acc[4][4] = {{0.f}};

  for (int k0 = 0; k0 < Kd; k0 += 32) {
#pragma unroll
    for (int jj = 0; jj < 2; ++jj) {
      int idx = t + jj * 256;
      int r = idx >> 3, kq = idx & 7;
      float4 va = *reinterpret_cast<const float4*>(&A[(size_t)(row0 + r) * Kd + k0 + kq * 4]);
      As[r][kq*4+0] = va.x; As[r][kq*4+1] = va.y; As[r][kq*4+2] = va.z; As[r][kq*4+3] = va.w;
      float4 vw = *reinterpret_cast<const float4*>(&W[(size_t)(col0 + r) * Kd + k0 + kq * 4]);
      Ws[r][kq*4+0] = vw.x; Ws[r][kq*4+1] = vw.y; Ws[r][kq*4+2] = vw.z; Ws[r][kq*4+3] = vw.w;
    }
    __syncthreads();
#pragma unroll
    for (int kk = 0; kk < 32; ++kk) {
      float a[4], b[4];
#pragma unroll
      for (int i = 0; i < 4; ++i) a[i] = As[ty + 16*i][kk];
#pragma unroll
      for (int j = 0; j < 4; ++j) b[j] = Ws[tx + 16*j][kk];
#pragma unroll
      for (int i = 0; i < 4; ++i)
#pragma unroll
        for (int j = 0; j < 4; ++j) acc[i][j] = fmaf(a[i], b[j], acc[i][j]);
    }
    __syncthreads();
  }

#pragma unroll
  for (int i = 0; i < 4; ++i)
#pragma unroll
    for (int j = 0; j < 4; ++j) {
      int r = row0 + ty + 16*i, o = col0 + tx + 16*j;
      float v = acc[i][j] + bias[o];
      if (head_layout) {
        int b = r >> 11, tt = r & (T_SEQ - 1);
        int h = o >> 6, dk = o & 63;
        out[(((size_t)b * N_HEADS + h) * T_SEQ + tt) * D_HEAD + dk] = v;
      } else {
        out[(size_t)r * N + o] = v;
      }
    }
}

// ---------------------------------------------------------------------------
// fp64 GEMM (head layout): out = A @ W^T + bias in double. Used for Q,K so the
// top-k selection is computed to f64 fidelity (matches the f64 numpy ref).
// ---------------------------------------------------------------------------
__global__ __launch_bounds__(256)
void gemm_f64_head(const float* __restrict__ A, const float* __restrict__ W,
                   const float* __restrict__ bias, double* __restrict__ out, int Kd)
{
  __shared__ double As[64][33];
  __shared__ double Ws[64][33];
  const int t = threadIdx.x;
  const int row0 = blockIdx.x * 64, col0 = blockIdx.y * 64;
  const int ty = t >> 4, tx = t & 15;
  double acc[4][4] = {{0.0}};

  for (int k0 = 0; k0 < Kd; k0 += 32) {
#pragma unroll
    for (int jj = 0; jj < 2; ++jj) {
      int idx = t + jj * 256;
      int r = idx >> 3, kq = idx & 7;
      float4 va = *reinterpret_cast<const float4*>(&A[(size_t)(row0 + r) * Kd + k0 + kq * 4]);
      As[r][kq*4+0] = (double)va.x; As[r][kq*4+1] = (double)va.y;
      As[r][kq*4+2] = (double)va.z; As[r][kq*4+3] = (double)va.w;
      float4 vw = *reinterpret_cast<const float4*>(&W[(size_t)(col0 + r) * Kd + k0 + kq * 4]);
      Ws[r][kq*4+0] = (double)vw.x; Ws[r][kq*4+1] = (double)vw.y;
      Ws[r][kq*4+2] = (double)vw.z; Ws[r][kq*4+3] = (double)vw.w;
    }
    __syncthreads();
#pragma unroll
    for (int kk = 0; kk < 32; ++kk) {
      double a[4], b[4];
#pragma unroll
      for (int i = 0; i < 4; ++i) a[i] = As[ty + 16*i][kk];
#pragma unroll
      for (int j = 0; j < 4; ++j) b[j] = Ws[tx + 16*j][kk];
#pragma unroll
      for (int i = 0; i < 4; ++i)
#pragma unroll
        for (int j = 0; j < 4; ++j) acc[i][j] = fma(a[i], b[j], acc[i][j]);
    }
    __syncthreads();
  }

#pragma unroll
  for (int i = 0; i < 4; ++i)
#pragma unroll
    for (int j = 0; j < 4; ++j) {
      int r = row0 + ty + 16*i, o = col0 + tx + 16*j;
      double v = acc[i][j] + (double)bias[o];
      int b = r >> 11, tt = r & (T_SEQ - 1);
      int h = o >> 6, dk = o & 63;
      out[(((size_t)b * N_HEADS + h) * T_SEQ + tt) * D_HEAD + dk] = v;
    }
}

// ---------------------------------------------------------------------------
// Fused attention, fp64 score path:
//   scores (f64) -> exact top-64 threshold (64-bit MSB-first binary search on
//   the monotone key; counts via direct f64 compares against the decoded
//   wave-uniform pivot) -> laplace weights (f64 erf) -> PV (f32).
// Block = 256 threads = 4 waves = 4 q-rows of one (b,h).
// ---------------------------------------------------------------------------
__global__ __launch_bounds__(256)
void attn_kern64(const double* __restrict__ Q, const double* __restrict__ K,
                 const float* __restrict__ V, const int* __restrict__ mask,
                 float* __restrict__ X)
{
  __shared__ double q4[4][64];          // 2 KB
  __shared__ double Ks[64][65];         // 33.3 KB (pad 65: 2-way max on b64)
  __shared__ double part[4][4][64];     // 8 KB   [d-group][row][k]
  __shared__ double sc[4][2048];        // 64 KB  f64 scores
  __shared__ int    lidx[4][CAP];       // 4 KB
  __shared__ float  lwt[4][CAP];        // 4 KB

  const int t  = threadIdx.x;
  const int bh = blockIdx.y;
  const int b  = bh >> 4, h = bh & 15;
  const int q0 = blockIdx.x * 4;
  const size_t kvbase = (size_t)bh * T_SEQ * D_HEAD;
  const int lane = t & 63, wv = t >> 6;

  q4[wv][lane] = Q[kvbase + (size_t)(q0 + wv) * D_HEAD + lane];
  __syncthreads();

  // ---- score phase: chunks of 64 k-rows; thread (kl, grp) computes the
  // d-range [16*grp,16*grp+16) partial dot for ALL 4 rows (1 K-read -> 4 FMA)
  const int kl = lane, grp = wv;
  for (int c = 0; c < T_SEQ / 64; ++c) {
#pragma unroll
    for (int jj = 0; jj < 16; ++jj) {
      int idx = t + jj * 256;            // 0..4095 doubles
      int kr = idx >> 6, d = idx & 63;
      Ks[kr][d] = K[kvbase + (size_t)(c * 64 + kr) * D_HEAD + d];
    }
    __syncthreads();
    double p0 = 0, p1 = 0, p2 = 0, p3 = 0;
    const int d0 = grp * 16;
#pragma unroll
    for (int dd = 0; dd < 16; ++dd) {
      double kv = Ks[kl][d0 + dd];
      p0 = fma(kv, q4[0][d0 + dd], p0);
      p1 = fma(kv, q4[1][d0 + dd], p1);
      p2 = fma(kv, q4[2][d0 + dd], p2);
      p3 = fma(kv, q4[3][d0 + dd], p3);
    }
    part[grp][0][kl] = p0; part[grp][1][kl] = p1;
    part[grp][2][kl] = p2; part[grp][3][kl] = p3;
    __syncthreads();
    // combine: thread (kl, grp) finishes row = grp at k = c*64+kl
    double sv = part[0][grp][kl] + part[1][grp][kl] + part[2][grp][kl] + part[3][grp][kl];
    sc[grp][c * 64 + kl] = sv * 0.125;   // /sqrt(64), exact
    __syncthreads();
  }

  // ---- selection: wave wv owns q-row q0+wv; 32 f64 scores/lane in regs ----
  double s[32];
#pragma unroll
  for (int j = 0; j < 32; ++j) s[j] = sc[wv][j * 64 + lane];

  unsigned long long p = 0ull;           // converges to mono-key of 64th-largest
  for (int bit = 63; bit >= 0; --bit) {
    unsigned long long cand = p | (1ull << bit);
    double cd = key2d(cand);             // wave-uniform pivot as a double
    int cnt = 0;
#pragma unroll
    for (int j = 0; j < 32; ++j) cnt += (s[j] >= cd) ? 1 : 0;
#pragma unroll
    for (int off = 32; off >= 1; off >>= 1) cnt += __shfl_xor(cnt, off);
    if (cnt >= TOPK_N) p = cand;
  }
  const double pd = key2d(p);            // exact f64 64th-largest score

  // ---- compaction: kept = (score >= vk) && !mask (mask AFTER top-k, as ref)
  const int qrow = q0 + wv;
  const size_t mbase = ((size_t)b * T_SEQ + qrow) * T_SEQ;
  int total = 0;
  for (int j = 0; j < 32; ++j) {
    int k = j * 64 + lane;
    bool keep = (s[j] >= pd);
    if (keep) keep = (mask[mbase + k] == 0);
    unsigned long long bal = __ballot(keep);
    if (keep) {
      int pos = total + (int)__builtin_popcountll(bal & ((1ull << lane) - 1ull));
      if (pos < CAP) {
        lidx[wv][pos] = k;
        lwt[wv][pos]  = (float)(0.5 * (1.0 + erf((s[j] - LAP_MU) * LAP_INV)));
      }
    }
    total += (int)__builtin_popcountll(bal);
  }
  __syncthreads();

  // ---- PV: broadcast (k, w) list; lane owns output dim d=lane ----
  int n = total < CAP ? total : CAP;
  float acc = 0.f;
  for (int e = 0; e < n; ++e) {
    acc = fmaf(lwt[wv][e], V[kvbase + (size_t)lidx[wv][e] * D_HEAD + lane], acc);
  }
  X[((size_t)b * T_SEQ + qrow) * D_MODEL + h * D_HEAD + lane] = acc;
}

// ---------------------------------------------------------------------------
extern "C" void kernel_launch(void* const* d_in, const int* in_sizes, int n_in,
                              void* d_out, int out_size, void* d_ws, size_t ws_size,
                              hipStream_t stream)
{
  const float* query = (const float*)d_in[0];
  const float* key_  = (const float*)d_in[1];
  const float* value = (const float*)d_in[2];
  const int*   mask  = (const int*)d_in[3];
  const float* wq = (const float*)d_in[4];
  const float* bq = (const float*)d_in[5];
  const float* wk = (const float*)d_in[6];
  const float* bk = (const float*)d_in[7];
  const float* wvp = (const float*)d_in[8];
  const float* bv = (const float*)d_in[9];
  const float* wo = (const float*)d_in[10];
  const float* bo = (const float*)d_in[11];
  float* out = (float*)d_out;

  // workspace (96 MiB): Qd,Kd f64 [b][h][t][dk]; Vb f32 [b][h][t][dk]; Xb f32 [b][t][d]
  double* Qd = (double*)d_ws;
  double* Kd = (double*)((char*)d_ws + ((size_t)32 << 20));
  float*  Vb = (float*)((char*)d_ws + ((size_t)64 << 20));
  float*  Xb = (float*)((char*)d_ws + ((size_t)80 << 20));

  const int M = N_B * T_SEQ;   // 4096
  dim3 gg(M / 64, D_MODEL / 64), bb(256);
  hipLaunchKernelGGL(gemm_f64_head, gg, bb, 0, stream, query, wq, bq, Qd, D_MODEL);
  hipLaunchKernelGGL(gemm_f64_head, gg, bb, 0, stream, key_,  wk, bk, Kd, D_MODEL);
  hipLaunchKernelGGL(gemm_nt,       gg, bb, 0, stream, value, wvp, bv, Vb, M, D_MODEL, D_MODEL, 1);

  dim3 ga(T_SEQ / 4, N_B * N_HEADS);
  hipLaunchKernelGGL(attn_kern64, ga, dim3(256), 0, stream, Qd, Kd, Vb, mask, Xb);

  hipLaunchKernelGGL(gemm_nt, gg, bb, 0, stream, Xb, wo, bo, out, M, D_MODEL, D_MODEL, 0);
}

// Round 3
// 2999.601 us; speedup vs baseline: 2.4830x; 2.4830x over previous
//
#include <hip/hip_runtime.h>
#include <math.h>

// Problem constants
#define N_B     2
#define T_SEQ   2048
#define D_MODEL 1024
#define N_HEADS 16
#define D_HEAD  64
#define TOPK_N  64
#define CAND    128   // max band candidates per row (64 + slack)
#define QROWS   8     // q-rows per block
#define RPW     2     // q-rows per wave

// laplace(x) = 0.5*(1+erf((x-mu)*sqrt(2/pi))), mu=sqrt(.5)
#define LAP_MU_F  0.70710678f
#define LAP_INV_F 0.79788456f

// decode monotone keys back to float/double
__device__ __forceinline__ float key2f(unsigned k) {
  unsigned b = (k & 0x80000000u) ? (k & 0x7fffffffu) : ~k;
  return __uint_as_float(b);
}
__device__ __forceinline__ double key2d(unsigned long long k) {
  unsigned long long b = (k & 0x8000000000000000ull) ? (k & 0x7fffffffffffffffull) : ~k;
  return __longlong_as_double((long long)b);
}

// ---------------------------------------------------------------------------
// fp32 GEMM: out = A @ W^T + bias (V-projection, out-projection).
// ---------------------------------------------------------------------------
__global__ __launch_bounds__(256)
void gemm_nt(const float* __restrict__ A, const float* __restrict__ W,
             const float* __restrict__ bias, float* __restrict__ out,
             int M, int N, int Kd, int head_layout)
{
  __shared__ float As[64][33];
  __shared__ float Ws[64][33];
  const int t = threadIdx.x;
  const int row0 = blockIdx.x * 64, col0 = blockIdx.y * 64;
  const int ty = t >> 4, tx = t & 15;
  float acc[4][4] = {{0.f}};

  for (int k0 = 0; k0 < Kd; k0 += 32) {
#pragma unroll
    for (int jj = 0; jj < 2; ++jj) {
      int idx = t + jj * 256;
      int r = idx >> 3, kq = idx & 7;
      float4 va = *reinterpret_cast<const float4*>(&A[(size_t)(row0 + r) * Kd + k0 + kq * 4]);
      As[r][kq*4+0] = va.x; As[r][kq*4+1] = va.y; As[r][kq*4+2] = va.z; As[r][kq*4+3] = va.w;
      float4 vw = *reinterpret_cast<const float4*>(&W[(size_t)(col0 + r) * Kd + k0 + kq * 4]);
      Ws[r][kq*4+0] = vw.x; Ws[r][kq*4+1] = vw.y; Ws[r][kq*4+2] = vw.z; Ws[r][kq*4+3] = vw.w;
    }
    __syncthreads();
#pragma unroll
    for (int kk = 0; kk < 32; ++kk) {
      float a[4], b[4];
#pragma unroll
      for (int i = 0; i < 4; ++i) a[i] = As[ty + 16*i][kk];
#pragma unroll
      for (int j = 0; j < 4; ++j) b[j] = Ws[tx + 16*j][kk];
#pragma unroll
      for (int i = 0; i < 4; ++i)
#pragma unroll
        for (int j = 0; j < 4; ++j) acc[i][j] = fmaf(a[i], b[j], acc[i][j]);
    }
    __syncthreads();
  }

#pragma unroll
  for (int i = 0; i < 4; ++i)
#pragma unroll
    for (int j = 0; j < 4; ++j) {
      int r = row0 + ty + 16*i, o = col0 + tx + 16*j;
      float v = acc[i][j] + bias[o];
      if (head_layout) {
        int b = r >> 11, tt = r & (T_SEQ - 1);
        int h = o >> 6, dk = o & 63;
        out[(((size_t)b * N_HEADS + h) * T_SEQ + tt) * D_HEAD + dk] = v;
      } else {
        out[(size_t)r * N + o] = v;
      }
    }
}

// ---------------------------------------------------------------------------
// fp64 GEMM (head layout) for Q,K; optionally writes an fp32 copy (for the
// fast fp32 score pass).
// ---------------------------------------------------------------------------
__global__ __launch_bounds__(256)
void gemm_f64_head(const float* __restrict__ A, const float* __restrict__ W,
                   const float* __restrict__ bias, double* __restrict__ out,
                   float* __restrict__ out32, int Kd)
{
  __shared__ double As[64][33];
  __shared__ double Ws[64][33];
  const int t = threadIdx.x;
  const int row0 = blockIdx.x * 64, col0 = blockIdx.y * 64;
  const int ty = t >> 4, tx = t & 15;
  double acc[4][4] = {{0.0}};

  for (int k0 = 0; k0 < Kd; k0 += 32) {
#pragma unroll
    for (int jj = 0; jj < 2; ++jj) {
      int idx = t + jj * 256;
      int r = idx >> 3, kq = idx & 7;
      float4 va = *reinterpret_cast<const float4*>(&A[(size_t)(row0 + r) * Kd + k0 + kq * 4]);
      As[r][kq*4+0] = (double)va.x; As[r][kq*4+1] = (double)va.y;
      As[r][kq*4+2] = (double)va.z; As[r][kq*4+3] = (double)va.w;
      float4 vw = *reinterpret_cast<const float4*>(&W[(size_t)(col0 + r) * Kd + k0 + kq * 4]);
      Ws[r][kq*4+0] = (double)vw.x; Ws[r][kq*4+1] = (double)vw.y;
      Ws[r][kq*4+2] = (double)vw.z; Ws[r][kq*4+3] = (double)vw.w;
    }
    __syncthreads();
#pragma unroll
    for (int kk = 0; kk < 32; ++kk) {
      double a[4], b[4];
#pragma unroll
      for (int i = 0; i < 4; ++i) a[i] = As[ty + 16*i][kk];
#pragma unroll
      for (int j = 0; j < 4; ++j) b[j] = Ws[tx + 16*j][kk];
#pragma unroll
      for (int i = 0; i < 4; ++i)
#pragma unroll
        for (int j = 0; j < 4; ++j) acc[i][j] = fma(a[i], b[j], acc[i][j]);
    }
    __syncthreads();
  }

#pragma unroll
  for (int i = 0; i < 4; ++i)
#pragma unroll
    for (int j = 0; j < 4; ++j) {
      int r = row0 + ty + 16*i, o = col0 + tx + 16*j;
      double v = acc[i][j] + (double)bias[o];
      int b = r >> 11, tt = r & (T_SEQ - 1);
      int h = o >> 6, dk = o & 63;
      size_t oi = (((size_t)b * N_HEADS + h) * T_SEQ + tt) * D_HEAD + dk;
      out[oi] = v;
      if (out32) out32[oi] = (float)v;
    }
}

// ---------------------------------------------------------------------------
// Per-row tail: fp32 threshold -> band -> f64 refine -> exact vk -> weights
// -> PV.  Entirely wave-private (no barriers).
// ---------------------------------------------------------------------------
__device__ __forceinline__ void process_row(
    const float (&s)[32], int* __restrict__ lidx_row, float* __restrict__ lwt_row,
    const double* __restrict__ Qd, const double* __restrict__ Kd,
    const float* __restrict__ V, const int* __restrict__ mask,
    float* __restrict__ X, size_t kvbase, size_t mbase, size_t xbase,
    int qglob, int lane)
{
  // fp32 64th-largest via bitwise search (ballot counts; bits <12 skipped —
  // quantization ~1e-4 is absorbed by the band epsilon below)
  unsigned p = 0u;
  for (int bit = 31; bit >= 12; --bit) {
    unsigned cand = p | (1u << bit);
    float cf = key2f(cand);
    int cnt = 0;
#pragma unroll
    for (int j = 0; j < 32; ++j)
      cnt += (int)__popcll(__ballot(s[j] >= cf));
    if (cnt >= TOPK_N) p = cand;
  }
  const float thr = key2f(p) - 1e-3f;   // band: superset of the true f64 top-64

  // compact band candidates
  int total = 0;
#pragma unroll
  for (int j = 0; j < 32; ++j) {
    bool cnd = (s[j] >= thr);
    unsigned long long bal = __ballot(cnd);
    if (cnd) {
      int pos = total + (int)__popcll(bal & ((1ull << lane) - 1ull));
      if (pos < CAND) lidx_row[pos] = j * 64 + lane;
    }
    total += (int)__popcll(bal);
  }
  const int n = total < CAND ? total : CAND;

  // f64 refinement: exact scores for candidates (coalesced Kd reads)
  const double qd = Qd[kvbase + (size_t)qglob * D_HEAD + lane];
  double cs0 = -(double)INFINITY, cs1 = -(double)INFINITY;
  for (int e = 0; e < n; ++e) {
    int k = lidx_row[e];
    double prod = qd * Kd[kvbase + (size_t)k * D_HEAD + lane];
#pragma unroll
    for (int off = 32; off >= 1; off >>= 1)
      prod += __shfl_xor(prod, off);
    prod *= 0.125;                       // /sqrt(64), exact
    if (lane == (e & 63)) { if (e < 64) cs0 = prod; else cs1 = prod; }
  }

  // exact f64 64th-largest among candidates (= global vk; non-candidates < vk)
  unsigned long long P = 0ull;
  for (int bit = 63; bit >= 0; --bit) {
    unsigned long long cand = P | (1ull << bit);
    double cd = key2d(cand);
    int cnt = (int)__popcll(__ballot(lane < n && cs0 >= cd))
            + (int)__popcll(__ballot(64 + lane < n && cs1 >= cd));
    if (cnt >= TOPK_N) P = cand;
  }
  const double vk = key2d(P);

  // weights: kept = (s64 >= vk) && !mask; dropped candidates get weight 0
#pragma unroll
  for (int s2 = 0; s2 < 2; ++s2) {
    int e = s2 * 64 + lane;
    double cs = s2 ? cs1 : cs0;
    if (e < n) {
      int k = lidx_row[e];
      bool keep = (cs >= vk) && (mask[mbase + k] == 0);
      lwt_row[e] = keep ? 0.5f * (1.0f + erff(((float)cs - LAP_MU_F) * LAP_INV_F)) : 0.f;
    }
  }

  // PV: lane owns output dim d=lane
  float acc = 0.f;
  for (int e = 0; e < n; ++e)
    acc = fmaf(lwt_row[e], V[kvbase + (size_t)lidx_row[e] * D_HEAD + lane], acc);
  X[xbase + lane] = acc;
}

// ---------------------------------------------------------------------------
// Fused attention: fp32 bulk scores (regs) + f64 boundary refinement.
// Block = 256 threads = 4 waves; QROWS=8 q-rows (2 per wave) of one (b,h).
// ---------------------------------------------------------------------------
__global__ __launch_bounds__(256)
void attn_fused(const double* __restrict__ Qd, const double* __restrict__ Kd,
                const float* __restrict__ Ks32, const float* __restrict__ V,
                const int* __restrict__ mask, float* __restrict__ X)
{
  __shared__ float q8[QROWS][64];      // 2 KB
  __shared__ float KsT[128][68];       // 34.8 KB
  __shared__ int   lidx[QROWS][CAND];  // 4 KB
  __shared__ float lwt[QROWS][CAND];   // 4 KB

  const int t = threadIdx.x, wv = t >> 6, lane = t & 63;
  const int bh = blockIdx.y, b = bh >> 4, h = bh & 15;
  const int q0 = blockIdx.x * QROWS;
  const size_t kvbase = (size_t)bh * T_SEQ * D_HEAD;

  for (int i = t; i < QROWS * 64; i += 256)
    q8[i >> 6][i & 63] = (float)Qd[kvbase + (size_t)(q0 + (i >> 6)) * D_HEAD + (i & 63)];
  __syncthreads();

  const int r0 = wv * RPW;
  float s0[32], s1[32];

  for (int c = 0; c < T_SEQ / 128; ++c) {
#pragma unroll
    for (int jj = 0; jj < 8; ++jj) {
      int idx = t + jj * 256, kr = idx >> 4, dq = idx & 15;
      float4 v = *reinterpret_cast<const float4*>(
          &Ks32[kvbase + (size_t)(c * 128 + kr) * D_HEAD + dq * 4]);
      *reinterpret_cast<float4*>(&KsT[kr][dq * 4]) = v;
    }
    __syncthreads();
#pragma unroll
    for (int j = 0; j < 2; ++j) {
      int kl = j * 64 + lane;
      float a0 = 0.f, a1 = 0.f;
#pragma unroll
      for (int dq = 0; dq < 16; ++dq) {
        float4 kv = *reinterpret_cast<const float4*>(&KsT[kl][dq * 4]);
        float4 qa = *reinterpret_cast<const float4*>(&q8[r0][dq * 4]);
        float4 qb = *reinterpret_cast<const float4*>(&q8[r0 + 1][dq * 4]);
        a0 = fmaf(kv.x, qa.x, a0); a0 = fmaf(kv.y, qa.y, a0);
        a0 = fmaf(kv.z, qa.z, a0); a0 = fmaf(kv.w, qa.w, a0);
        a1 = fmaf(kv.x, qb.x, a1); a1 = fmaf(kv.y, qb.y, a1);
        a1 = fmaf(kv.z, qb.z, a1); a1 = fmaf(kv.w, qb.w, a1);
      }
      s0[c * 2 + j] = a0 * 0.125f;
      s1[c * 2 + j] = a1 * 0.125f;
    }
    __syncthreads();
  }

  // wave-private tails (no barriers needed: rows are owned by one wave)
  {
    const int lr = r0, qg = q0 + lr;
    process_row(s0, lidx[lr], lwt[lr], Qd, Kd, V, mask, X, kvbase,
                ((size_t)b * T_SEQ + qg) * T_SEQ, ((size_t)b * T_SEQ + qg) * D_MODEL + (size_t)h * D_HEAD,
                qg, lane);
  }
  {
    const int lr = r0 + 1, qg = q0 + lr;
    process_row(s1, lidx[lr], lwt[lr], Qd, Kd, V, mask, X, kvbase,
                ((size_t)b * T_SEQ + qg) * T_SEQ, ((size_t)b * T_SEQ + qg) * D_MODEL + (size_t)h * D_HEAD,
                qg, lane);
  }
}

// ---------------------------------------------------------------------------
extern "C" void kernel_launch(void* const* d_in, const int* in_sizes, int n_in,
                              void* d_out, int out_size, void* d_ws, size_t ws_size,
                              hipStream_t stream)
{
  const float* query = (const float*)d_in[0];
  const float* key_  = (const float*)d_in[1];
  const float* value = (const float*)d_in[2];
  const int*   mask  = (const int*)d_in[3];
  const float* wq = (const float*)d_in[4];
  const float* bq = (const float*)d_in[5];
  const float* wk = (const float*)d_in[6];
  const float* bk = (const float*)d_in[7];
  const float* wvp = (const float*)d_in[8];
  const float* bv = (const float*)d_in[9];
  const float* wo = (const float*)d_in[10];
  const float* bo = (const float*)d_in[11];
  float* out = (float*)d_out;

  // ws (96 MiB, round-2-proven): Qd f64 32M | Kd f64 32M | Ks32 f32 16M | Xb f32 16M
  double* Qd   = (double*)d_ws;
  double* Kd   = (double*)((char*)d_ws + ((size_t)32 << 20));
  float*  Ks32 = (float*) ((char*)d_ws + ((size_t)64 << 20));
  float*  Xb   = (float*) ((char*)d_ws + ((size_t)80 << 20));
  float*  Vb   = out;   // V-projection parks in d_out; final GEMM overwrites it

  const int M = N_B * T_SEQ;   // 4096
  dim3 gg(M / 64, D_MODEL / 64), bb(256);
  hipLaunchKernelGGL(gemm_f64_head, gg, bb, 0, stream, query, wq, bq, Qd, (float*)nullptr, D_MODEL);
  hipLaunchKernelGGL(gemm_f64_head, gg, bb, 0, stream, key_,  wk, bk, Kd, Ks32, D_MODEL);
  hipLaunchKernelGGL(gemm_nt,       gg, bb, 0, stream, value, wvp, bv, Vb, M, D_MODEL, D_MODEL, 1);

  dim3 ga(T_SEQ / QROWS, N_B * N_HEADS);
  hipLaunchKernelGGL(attn_fused, ga, dim3(256), 0, stream, Qd, Kd, Ks32, Vb, mask, Xb);

  hipLaunchKernelGGL(gemm_nt, gg, bb, 0, stream, Xb, wo, bo, out, M, D_MODEL, D_MODEL, 0);
}

// Round 4
// 2149.285 us; speedup vs baseline: 3.4653x; 1.3956x over previous
//
#include <hip/hip_runtime.h>
#include <math.h>

// Problem constants
#define N_B     2
#define T_SEQ   2048
#define D_MODEL 1024
#define N_HEADS 16
#define D_HEAD  64
#define TOPK_N  64
#define DCAP    80    // definite-in capacity (provably <= 63)
#define ACAP    32    // ambiguous-band capacity (expected 1-3)
#define QROWS   8     // q-rows per block
#define RPW     2     // q-rows per wave

// laplace(x) = 0.5*(1+erf((x-mu)*sqrt(2/pi))), mu=sqrt(.5)
#define LAP_MU_F  0.70710678f
#define LAP_INV_F 0.79788456f
// certified |s32 - s64| bound (true ~1e-6 rms; 100x margin)
#define EERR      1e-4f

// decode monotone key back to float
__device__ __forceinline__ float key2f(unsigned k) {
  unsigned b = (k & 0x80000000u) ? (k & 0x7fffffffu) : ~k;
  return __uint_as_float(b);
}

// ---------------------------------------------------------------------------
// fp32 GEMM: out = A @ W^T + bias (V-projection, out-projection).
// ---------------------------------------------------------------------------
__global__ __launch_bounds__(256)
void gemm_nt(const float* __restrict__ A, const float* __restrict__ W,
             const float* __restrict__ bias, float* __restrict__ out,
             int M, int N, int Kd, int head_layout)
{
  __shared__ float As[64][33];
  __shared__ float Ws[64][33];
  const int t = threadIdx.x;
  const int row0 = blockIdx.x * 64, col0 = blockIdx.y * 64;
  const int ty = t >> 4, tx = t & 15;
  float acc[4][4] = {{0.f}};

  for (int k0 = 0; k0 < Kd; k0 += 32) {
#pragma unroll
    for (int jj = 0; jj < 2; ++jj) {
      int idx = t + jj * 256;
      int r = idx >> 3, kq = idx & 7;
      float4 va = *reinterpret_cast<const float4*>(&A[(size_t)(row0 + r) * Kd + k0 + kq * 4]);
      As[r][kq*4+0] = va.x; As[r][kq*4+1] = va.y; As[r][kq*4+2] = va.z; As[r][kq*4+3] = va.w;
      float4 vw = *reinterpret_cast<const float4*>(&W[(size_t)(col0 + r) * Kd + k0 + kq * 4]);
      Ws[r][kq*4+0] = vw.x; Ws[r][kq*4+1] = vw.y; Ws[r][kq*4+2] = vw.z; Ws[r][kq*4+3] = vw.w;
    }
    __syncthreads();
#pragma unroll
    for (int kk = 0; kk < 32; ++kk) {
      float a[4], b[4];
#pragma unroll
      for (int i = 0; i < 4; ++i) a[i] = As[ty + 16*i][kk];
#pragma unroll
      for (int j = 0; j < 4; ++j) b[j] = Ws[tx + 16*j][kk];
#pragma unroll
      for (int i = 0; i < 4; ++i)
#pragma unroll
        for (int j = 0; j < 4; ++j) acc[i][j] = fmaf(a[i], b[j], acc[i][j]);
    }
    __syncthreads();
  }

#pragma unroll
  for (int i = 0; i < 4; ++i)
#pragma unroll
    for (int j = 0; j < 4; ++j) {
      int r = row0 + ty + 16*i, o = col0 + tx + 16*j;
      float v = acc[i][j] + bias[o];
      if (head_layout) {
        int b = r >> 11, tt = r & (T_SEQ - 1);
        int h = o >> 6, dk = o & 63;
        out[(((size_t)b * N_HEADS + h) * T_SEQ + tt) * D_HEAD + dk] = v;
      } else {
        out[(size_t)r * N + o] = v;
      }
    }
}

// ---------------------------------------------------------------------------
// fp64 GEMM (head layout) for Q,K; optionally writes an fp32 copy.
// ---------------------------------------------------------------------------
__global__ __launch_bounds__(256)
void gemm_f64_head(const float* __restrict__ A, const float* __restrict__ W,
                   const float* __restrict__ bias, double* __restrict__ out,
                   float* __restrict__ out32, int Kd)
{
  __shared__ double As[64][33];
  __shared__ double Ws[64][33];
  const int t = threadIdx.x;
  const int row0 = blockIdx.x * 64, col0 = blockIdx.y * 64;
  const int ty = t >> 4, tx = t & 15;
  double acc[4][4] = {{0.0}};

  for (int k0 = 0; k0 < Kd; k0 += 32) {
#pragma unroll
    for (int jj = 0; jj < 2; ++jj) {
      int idx = t + jj * 256;
      int r = idx >> 3, kq = idx & 7;
      float4 va = *reinterpret_cast<const float4*>(&A[(size_t)(row0 + r) * Kd + k0 + kq * 4]);
      As[r][kq*4+0] = (double)va.x; As[r][kq*4+1] = (double)va.y;
      As[r][kq*4+2] = (double)va.z; As[r][kq*4+3] = (double)va.w;
      float4 vw = *reinterpret_cast<const float4*>(&W[(size_t)(col0 + r) * Kd + k0 + kq * 4]);
      Ws[r][kq*4+0] = (double)vw.x; Ws[r][kq*4+1] = (double)vw.y;
      Ws[r][kq*4+2] = (double)vw.z; Ws[r][kq*4+3] = (double)vw.w;
    }
    __syncthreads();
#pragma unroll
    for (int kk = 0; kk < 32; ++kk) {
      double a[4], b[4];
#pragma unroll
      for (int i = 0; i < 4; ++i) a[i] = As[ty + 16*i][kk];
#pragma unroll
      for (int j = 0; j < 4; ++j) b[j] = Ws[tx + 16*j][kk];
#pragma unroll
      for (int i = 0; i < 4; ++i)
#pragma unroll
        for (int j = 0; j < 4; ++j) acc[i][j] = fma(a[i], b[j], acc[i][j]);
    }
    __syncthreads();
  }

#pragma unroll
  for (int i = 0; i < 4; ++i)
#pragma unroll
    for (int j = 0; j < 4; ++j) {
      int r = row0 + ty + 16*i, o = col0 + tx + 16*j;
      double v = acc[i][j] + (double)bias[o];
      int b = r >> 11, tt = r & (T_SEQ - 1);
      int h = o >> 6, dk = o & 63;
      size_t oi = (((size_t)b * N_HEADS + h) * T_SEQ + tt) * D_HEAD + dk;
      out[oi] = v;
      if (out32) out32[oi] = (float)v;
    }
}

// ---------------------------------------------------------------------------
// Per-row tail with certified bands:
//  fp32 pivot (bits 31..8) -> definite-in (s32>=hi, provably top-64) +
//  ambiguous band A (lo<=s32<hi, expected 1-3) -> lane-parallel f64 scores
//  for A only -> rank among A (top `need` kept; ties kept, = ref's >=vk) ->
//  laplace weights -> PV.  Entirely wave-private.
// ---------------------------------------------------------------------------
__device__ __forceinline__ void process_row(
    const float (&s)[32], int* __restrict__ dkl, float* __restrict__ dwl,
    int* __restrict__ akl, float* __restrict__ awl,
    const double* __restrict__ q64, const double* __restrict__ Kd,
    const float* __restrict__ V, const int* __restrict__ mask,
    float* __restrict__ X, size_t kvbase, size_t mbase, size_t xbase, int lane)
{
  // exact fp32 64th-largest to 256-ulp resolution (mono-key bit search)
  unsigned p = 0u;
  for (int bit = 31; bit >= 8; --bit) {
    unsigned cand = p | (1u << bit);
    float cf = key2f(cand);
    int cnt = 0;
#pragma unroll
    for (int j = 0; j < 32; ++j) cnt += (int)__popcll(__ballot(s[j] >= cf));
    if (cnt >= TOPK_N) p = cand;
  }
  const float pv = key2f(p);          // pv <= v32
  const float pn = key2f(p + 256u);   // v32 < pn
  const float hi = pn + 2.f * EERR;   // s32>=hi  => certainly in f64 top-64
  const float lo = pv - 2.f * EERR;   // s32<lo   => certainly out

  // compact definite list (with weights) and ambiguous list
  int m = 0, na = 0;
#pragma unroll
  for (int j = 0; j < 32; ++j) {
    float sv = s[j];
    bool isd = (sv >= hi);
    bool isa = (sv >= lo) && !isd;
    unsigned long long bd = __ballot(isd);
    unsigned long long ba = __ballot(isa);
    int k = j * 64 + lane;
    if (isd) {
      int pos = m + (int)__popcll(bd & ((1ull << lane) - 1ull));
      if (pos < DCAP) {
        dkl[pos] = k;
        dwl[pos] = (mask[mbase + k] != 0) ? 0.f
                 : 0.5f * (1.f + erff((sv - LAP_MU_F) * LAP_INV_F));
      }
    }
    if (isa) {
      int pos = na + (int)__popcll(ba & ((1ull << lane) - 1ull));
      if (pos < ACAP) akl[pos] = k;
    }
    m += (int)__popcll(bd);
    na += (int)__popcll(ba);
  }
  if (m > DCAP) m = DCAP;    // unreachable (m <= 63)
  if (na > ACAP) na = ACAP;  // practically unreachable
  const int need = TOPK_N - m;   // >= 1, and <= na by construction

  // lane-parallel f64 refine of ambiguous candidates (lane e owns akl[e])
  int ke = akl[lane < na ? lane : 0];
  const double* kr = &Kd[kvbase + (size_t)ke * D_HEAD];
  double a0 = 0, a1 = 0, a2 = 0, a3 = 0;
#pragma unroll
  for (int d = 0; d < 64; d += 4) {
    a0 = fma(q64[d + 0], kr[d + 0], a0);
    a1 = fma(q64[d + 1], kr[d + 1], a1);
    a2 = fma(q64[d + 2], kr[d + 2], a2);
    a3 = fma(q64[d + 3], kr[d + 3], a3);
  }
  double s64e = ((a0 + a1) + (a2 + a3)) * 0.125;

  // rank among A by exact f64 (strict >): rank<need <=> s64 >= vk (ties kept)
  int rank = 0;
  for (int i = 0; i < na; ++i) {
    double vi = __shfl(s64e, i);
    rank += (vi > s64e) ? 1 : 0;
  }
  if (lane < na) {
    bool keep = (rank < need) && (mask[mbase + akl[lane]] == 0);
    awl[lane] = keep ? 0.5f * (1.f + erff(((float)s64e - LAP_MU_F) * LAP_INV_F)) : 0.f;
  }

  // PV: lane owns output dim d=lane
  float acc = 0.f;
  for (int e = 0; e < m; ++e)
    acc = fmaf(dwl[e], V[kvbase + (size_t)dkl[e] * D_HEAD + lane], acc);
  for (int e = 0; e < na; ++e)
    acc = fmaf(awl[e], V[kvbase + (size_t)akl[e] * D_HEAD + lane], acc);
  X[xbase + lane] = acc;
}

// ---------------------------------------------------------------------------
// Fused attention. Block = 256 threads = 4 waves, QROWS=8 (2 rows/wave).
// Score phase: d-blocked (4 x 16 dims), q hoisted to registers, K chunk
// [512][16] f32 in LDS with float4-slot XOR swizzle (uniform bank coverage).
// ---------------------------------------------------------------------------
__global__ __launch_bounds__(256)
void attn_fused(const double* __restrict__ Qd, const double* __restrict__ Kd,
                const float* __restrict__ K32, const float* __restrict__ V,
                const int* __restrict__ mask, float* __restrict__ X)
{
  __shared__ float  KsL[512 * 16];       // 32 KB swizzled K chunk
  __shared__ float  q8[QROWS][68];       // 2.1 KB
  __shared__ double q8d[QROWS][64];      // 4 KB
  __shared__ int    dk_l[QROWS][DCAP];   // 2.5 KB
  __shared__ float  dw_l[QROWS][DCAP];   // 2.5 KB
  __shared__ int    ak_l[QROWS][ACAP];   // 1 KB
  __shared__ float  aw_l[QROWS][ACAP];   // 1 KB

  const int t = threadIdx.x, wv = t >> 6, lane = t & 63;
  const int bh = blockIdx.y, b = bh >> 4, h = bh & 15;
  const int q0 = blockIdx.x * QROWS;
  const size_t kvbase = (size_t)bh * T_SEQ * D_HEAD;

  for (int i = t; i < QROWS * 64; i += 256) {
    int r = i >> 6, d = i & 63;
    double qv = Qd[kvbase + (size_t)(q0 + r) * D_HEAD + d];
    q8d[r][d] = qv;
    q8[r][d] = (float)qv;
  }
  __syncthreads();

  const int r0 = wv * RPW;
  float s0[32], s1[32];
#pragma unroll
  for (int j = 0; j < 32; ++j) { s0[j] = 0.f; s1[j] = 0.f; }

  for (int db = 0; db < 4; ++db) {
    float4 qa[4], qb[4];
#pragma unroll
    for (int qq = 0; qq < 4; ++qq) {
      qa[qq] = *reinterpret_cast<const float4*>(&q8[r0][db * 16 + qq * 4]);
      qb[qq] = *reinterpret_cast<const float4*>(&q8[r0 + 1][db * 16 + qq * 4]);
    }
    for (int kc = 0; kc < 4; ++kc) {
      // stage 512 rows x 16 dims (swizzled slots)
#pragma unroll
      for (int jj = 0; jj < 8; ++jj) {
        int idx = t + jj * 256;
        int r = idx >> 2, dq = idx & 3;
        float4 v = *reinterpret_cast<const float4*>(
            &K32[kvbase + (size_t)(kc * 512 + r) * D_HEAD + db * 16 + dq * 4]);
        int slot = dq ^ ((r >> 1) & 3);
        *reinterpret_cast<float4*>(&KsL[r * 16 + slot * 4]) = v;
      }
      __syncthreads();
#pragma unroll
      for (int i = 0; i < 8; ++i) {
        int kr2 = i * 64 + lane;
        int sw = (kr2 >> 1) & 3;
        const float* kp = &KsL[kr2 * 16];
        float4 k0 = *reinterpret_cast<const float4*>(&kp[(0 ^ sw) * 4]);
        float4 k1 = *reinterpret_cast<const float4*>(&kp[(1 ^ sw) * 4]);
        float4 k2 = *reinterpret_cast<const float4*>(&kp[(2 ^ sw) * 4]);
        float4 k3 = *reinterpret_cast<const float4*>(&kp[(3 ^ sw) * 4]);
        int j = kc * 8 + i;
        float a = s0[j], c = s1[j];
        a = fmaf(k0.x, qa[0].x, a); a = fmaf(k0.y, qa[0].y, a);
        a = fmaf(k0.z, qa[0].z, a); a = fmaf(k0.w, qa[0].w, a);
        a = fmaf(k1.x, qa[1].x, a); a = fmaf(k1.y, qa[1].y, a);
        a = fmaf(k1.z, qa[1].z, a); a = fmaf(k1.w, qa[1].w, a);
        a = fmaf(k2.x, qa[2].x, a); a = fmaf(k2.y, qa[2].y, a);
        a = fmaf(k2.z, qa[2].z, a); a = fmaf(k2.w, qa[2].w, a);
        a = fmaf(k3.x, qa[3].x, a); a = fmaf(k3.y, qa[3].y, a);
        a = fmaf(k3.z, qa[3].z, a); a = fmaf(k3.w, qa[3].w, a);
        c = fmaf(k0.x, qb[0].x, c); c = fmaf(k0.y, qb[0].y, c);
        c = fmaf(k0.z, qb[0].z, c); c = fmaf(k0.w, qb[0].w, c);
        c = fmaf(k1.x, qb[1].x, c); c = fmaf(k1.y, qb[1].y, c);
        c = fmaf(k1.z, qb[1].z, c); c = fmaf(k1.w, qb[1].w, c);
        c = fmaf(k2.x, qb[2].x, c); c = fmaf(k2.y, qb[2].y, c);
        c = fmaf(k2.z, qb[2].z, c); c = fmaf(k2.w, qb[2].w, c);
        c = fmaf(k3.x, qb[3].x, c); c = fmaf(k3.y, qb[3].y, c);
        c = fmaf(k3.z, qb[3].z, c); c = fmaf(k3.w, qb[3].w, c);
        s0[j] = a; s1[j] = c;
      }
      __syncthreads();
    }
  }
#pragma unroll
  for (int j = 0; j < 32; ++j) { s0[j] *= 0.125f; s1[j] *= 0.125f; }

  // wave-private tails
  {
    const int lr = r0, qg = q0 + lr;
    process_row(s0, dk_l[lr], dw_l[lr], ak_l[lr], aw_l[lr], q8d[lr],
                Kd, V, mask, X, kvbase,
                ((size_t)b * T_SEQ + qg) * T_SEQ,
                ((size_t)b * T_SEQ + qg) * D_MODEL + (size_t)h * D_HEAD, lane);
  }
  {
    const int lr = r0 + 1, qg = q0 + lr;
    process_row(s1, dk_l[lr], dw_l[lr], ak_l[lr], aw_l[lr], q8d[lr],
                Kd, V, mask, X, kvbase,
                ((size_t)b * T_SEQ + qg) * T_SEQ,
                ((size_t)b * T_SEQ + qg) * D_MODEL + (size_t)h * D_HEAD, lane);
  }
}

// ---------------------------------------------------------------------------
extern "C" void kernel_launch(void* const* d_in, const int* in_sizes, int n_in,
                              void* d_out, int out_size, void* d_ws, size_t ws_size,
                              hipStream_t stream)
{
  const float* query = (const float*)d_in[0];
  const float* key_  = (const float*)d_in[1];
  const float* value = (const float*)d_in[2];
  const int*   mask  = (const int*)d_in[3];
  const float* wq = (const float*)d_in[4];
  const float* bq = (const float*)d_in[5];
  const float* wk = (const float*)d_in[6];
  const float* bk = (const float*)d_in[7];
  const float* wvp = (const float*)d_in[8];
  const float* bv = (const float*)d_in[9];
  const float* wo = (const float*)d_in[10];
  const float* bo = (const float*)d_in[11];
  float* out = (float*)d_out;

  // ws (96 MiB): Qd f64 32M | Kd f64 32M | Ks32 f32 16M | Xb f32 16M
  double* Qd   = (double*)d_ws;
  double* Kd   = (double*)((char*)d_ws + ((size_t)32 << 20));
  float*  Ks32 = (float*) ((char*)d_ws + ((size_t)64 << 20));
  float*  Xb   = (float*) ((char*)d_ws + ((size_t)80 << 20));
  float*  Vb   = out;   // V-projection parks in d_out; final GEMM overwrites it

  const int M = N_B * T_SEQ;   // 4096
  dim3 gg(M / 64, D_MODEL / 64), bb(256);
  hipLaunchKernelGGL(gemm_f64_head, gg, bb, 0, stream, query, wq, bq, Qd, (float*)nullptr, D_MODEL);
  hipLaunchKernelGGL(gemm_f64_head, gg, bb, 0, stream, key_,  wk, bk, Kd, Ks32, D_MODEL);
  hipLaunchKernelGGL(gemm_nt,       gg, bb, 0, stream, value, wvp, bv, Vb, M, D_MODEL, D_MODEL, 1);

  dim3 ga(T_SEQ / QROWS, N_B * N_HEADS);
  hipLaunchKernelGGL(attn_fused, ga, dim3(256), 0, stream, Qd, Kd, Ks32, Vb, mask, Xb);

  hipLaunchKernelGGL(gemm_nt, gg, bb, 0, stream, Xb, wo, bo, out, M, D_MODEL, D_MODEL, 0);
}

// Round 5
// 1815.618 us; speedup vs baseline: 4.1022x; 1.1838x over previous
//
#include <hip/hip_runtime.h>
#include <math.h>

// Problem constants
#define N_B     2
#define T_SEQ   2048
#define D_MODEL 1024
#define N_HEADS 16
#define D_HEAD  64
#define TOPK_N  64
#define DCAP    80    // definite-in capacity (provably <= 63)
#define ACAP    32    // ambiguous-band capacity (expected 1-3)
#define QROWS   8     // q-rows per block
#define RPW     2     // q-rows per wave

// laplace(x) = 0.5*(1+erf((x-mu)*sqrt(2/pi))), mu=sqrt(.5)
#define LAP_MU_F  0.70710678f
#define LAP_INV_F 0.79788456f
// certified |s32 - s64| bound (true ~1e-6 rms; 100x margin)
#define EERR      1e-4f

#define AS1 __attribute__((address_space(1)))
#define AS3 __attribute__((address_space(3)))

typedef _Float16 f16x4 __attribute__((ext_vector_type(4)));
typedef _Float16 f16x8 __attribute__((ext_vector_type(8)));
typedef float    f32x4 __attribute__((ext_vector_type(4)));

// decode monotone key back to float
__device__ __forceinline__ float key2f(unsigned k) {
  unsigned b = (k & 0x80000000u) ? (k & 0x7fffffffu) : ~k;
  return __uint_as_float(b);
}

// ---------------------------------------------------------------------------
// f16-split MFMA GEMM: out = A @ W^T + bias.  A: MxK f32, W: NxK f32.
// Split a = a_hi + a_lo (f16 each); 3 MFMAs give ~f32-exact products
// (f16xf16 products are exact in f32; dropped lo*lo term ~2^-22 rel).
// W scaled x64 before split (keeps w_lo normal-f16), /64 in epilogue.
// Tile 64x64, BK=64, 4 waves each computing a 32x32 quadrant (2x2 MFMA tiles).
// C-layout per m89: col=lane&15, row=(lane>>4)*4+r.
// ---------------------------------------------------------------------------
__global__ __launch_bounds__(256)
void gemm_mfma_f16s(const float* __restrict__ A, const float* __restrict__ W,
                    const float* __restrict__ bias, float* __restrict__ out,
                    int M, int N, int Kd, int head_layout)
{
  __shared__ _Float16 Ah[64][72], Al[64][72], Bh[64][72], Bl[64][72]; // 36 KB

  const int t = threadIdx.x, lane = t & 63, wv = t >> 6;
  const int row0 = blockIdx.x * 64, col0 = blockIdx.y * 64;
  const int wr = (wv >> 1) * 32, wc = (wv & 1) * 32;
  f32x4 acc[2][2] = {};

  for (int k0 = 0; k0 < Kd; k0 += 64) {
#pragma unroll
    for (int jj = 0; jj < 4; ++jj) {
      int f = t + jj * 256;                 // 0..1023 float4s
      int r = f >> 4, kq = f & 15;
      float4 va = *reinterpret_cast<const float4*>(&A[(size_t)(row0 + r) * Kd + k0 + kq * 4]);
      f16x4 h, l;
      h[0] = (_Float16)va.x; l[0] = (_Float16)(va.x - (float)h[0]);
      h[1] = (_Float16)va.y; l[1] = (_Float16)(va.y - (float)h[1]);
      h[2] = (_Float16)va.z; l[2] = (_Float16)(va.z - (float)h[2]);
      h[3] = (_Float16)va.w; l[3] = (_Float16)(va.w - (float)h[3]);
      *reinterpret_cast<f16x4*>(&Ah[r][kq * 4]) = h;
      *reinterpret_cast<f16x4*>(&Al[r][kq * 4]) = l;
      float4 vw = *reinterpret_cast<const float4*>(&W[(size_t)(col0 + r) * Kd + k0 + kq * 4]);
      vw.x *= 64.f; vw.y *= 64.f; vw.z *= 64.f; vw.w *= 64.f;
      h[0] = (_Float16)vw.x; l[0] = (_Float16)(vw.x - (float)h[0]);
      h[1] = (_Float16)vw.y; l[1] = (_Float16)(vw.y - (float)h[1]);
      h[2] = (_Float16)vw.z; l[2] = (_Float16)(vw.z - (float)h[2]);
      h[3] = (_Float16)vw.w; l[3] = (_Float16)(vw.w - (float)h[3]);
      *reinterpret_cast<f16x4*>(&Bh[r][kq * 4]) = h;
      *reinterpret_cast<f16x4*>(&Bl[r][kq * 4]) = l;
    }
    __syncthreads();

#pragma unroll
    for (int ks = 0; ks < 2; ++ks) {
      const int koff = ks * 32 + (lane >> 4) * 8;   // frag k-range: (lane>>4)*8+j
      f16x8 a_h[2], a_l[2], b_h[2], b_l[2];
#pragma unroll
      for (int i = 0; i < 2; ++i) {
        int ar = wr + i * 16 + (lane & 15);
        a_h[i] = *reinterpret_cast<const f16x8*>(&Ah[ar][koff]);
        a_l[i] = *reinterpret_cast<const f16x8*>(&Al[ar][koff]);
        int bc = wc + i * 16 + (lane & 15);
        b_h[i] = *reinterpret_cast<const f16x8*>(&Bh[bc][koff]);
        b_l[i] = *reinterpret_cast<const f16x8*>(&Bl[bc][koff]);
      }
#pragma unroll
      for (int i = 0; i < 2; ++i)
#pragma unroll
        for (int j = 0; j < 2; ++j) {
          acc[i][j] = __builtin_amdgcn_mfma_f32_16x16x32_f16(a_h[i], b_h[j], acc[i][j], 0, 0, 0);
          acc[i][j] = __builtin_amdgcn_mfma_f32_16x16x32_f16(a_l[i], b_h[j], acc[i][j], 0, 0, 0);
          acc[i][j] = __builtin_amdgcn_mfma_f32_16x16x32_f16(a_h[i], b_l[j], acc[i][j], 0, 0, 0);
        }
    }
    __syncthreads();
  }

#pragma unroll
  for (int i = 0; i < 2; ++i)
#pragma unroll
    for (int j = 0; j < 2; ++j)
#pragma unroll
      for (int r = 0; r < 4; ++r) {
        int row = row0 + wr + i * 16 + ((lane >> 4) & 3) * 4 + r;
        int col = col0 + wc + j * 16 + (lane & 15);
        float v = acc[i][j][r] * 0.015625f + bias[col];   // /64 (exact)
        if (head_layout) {
          int b = row >> 11, tt = row & (T_SEQ - 1);
          int hh = col >> 6, dk = col & 63;
          out[(((size_t)b * N_HEADS + hh) * T_SEQ + tt) * D_HEAD + dk] = v;
        } else {
          out[(size_t)row * N + col] = v;
        }
      }
}

// ---------------------------------------------------------------------------
// fp64 GEMM (head layout) for Q,K; optionally writes an fp32 copy.
// ---------------------------------------------------------------------------
__global__ __launch_bounds__(256)
void gemm_f64_head(const float* __restrict__ A, const float* __restrict__ W,
                   const float* __restrict__ bias, double* __restrict__ out,
                   float* __restrict__ out32, int Kd)
{
  __shared__ double As[64][33];
  __shared__ double Ws[64][33];
  const int t = threadIdx.x;
  const int row0 = blockIdx.x * 64, col0 = blockIdx.y * 64;
  const int ty = t >> 4, tx = t & 15;
  double acc[4][4] = {{0.0}};

  for (int k0 = 0; k0 < Kd; k0 += 32) {
#pragma unroll
    for (int jj = 0; jj < 2; ++jj) {
      int idx = t + jj * 256;
      int r = idx >> 3, kq = idx & 7;
      float4 va = *reinterpret_cast<const float4*>(&A[(size_t)(row0 + r) * Kd + k0 + kq * 4]);
      As[r][kq*4+0] = (double)va.x; As[r][kq*4+1] = (double)va.y;
      As[r][kq*4+2] = (double)va.z; As[r][kq*4+3] = (double)va.w;
      float4 vw = *reinterpret_cast<const float4*>(&W[(size_t)(col0 + r) * Kd + k0 + kq * 4]);
      Ws[r][kq*4+0] = (double)vw.x; Ws[r][kq*4+1] = (double)vw.y;
      Ws[r][kq*4+2] = (double)vw.z; Ws[r][kq*4+3] = (double)vw.w;
    }
    __syncthreads();
#pragma unroll
    for (int kk = 0; kk < 32; ++kk) {
      double a[4], b[4];
#pragma unroll
      for (int i = 0; i < 4; ++i) a[i] = As[ty + 16*i][kk];
#pragma unroll
      for (int j = 0; j < 4; ++j) b[j] = Ws[tx + 16*j][kk];
#pragma unroll
      for (int i = 0; i < 4; ++i)
#pragma unroll
        for (int j = 0; j < 4; ++j) acc[i][j] = fma(a[i], b[j], acc[i][j]);
    }
    __syncthreads();
  }

#pragma unroll
  for (int i = 0; i < 4; ++i)
#pragma unroll
    for (int j = 0; j < 4; ++j) {
      int r = row0 + ty + 16*i, o = col0 + tx + 16*j;
      double v = acc[i][j] + (double)bias[o];
      int b = r >> 11, tt = r & (T_SEQ - 1);
      int h = o >> 6, dk = o & 63;
      size_t oi = (((size_t)b * N_HEADS + h) * T_SEQ + tt) * D_HEAD + dk;
      out[oi] = v;
      if (out32) out32[oi] = (float)v;
    }
}

// ---------------------------------------------------------------------------
// Per-row tail with certified bands (unchanged from round 4, proven).
// ---------------------------------------------------------------------------
__device__ __forceinline__ void process_row(
    const float (&s)[32], int* __restrict__ dkl, float* __restrict__ dwl,
    int* __restrict__ akl, float* __restrict__ awl,
    const double* __restrict__ q64, const double* __restrict__ Kd,
    const float* __restrict__ V, const int* __restrict__ mask,
    float* __restrict__ X, size_t kvbase, size_t mbase, size_t xbase, int lane)
{
  // exact fp32 64th-largest to 256-ulp resolution (mono-key bit search)
  unsigned p = 0u;
  for (int bit = 31; bit >= 8; --bit) {
    unsigned cand = p | (1u << bit);
    float cf = key2f(cand);
    int cnt = 0;
#pragma unroll
    for (int j = 0; j < 32; ++j) cnt += (int)__popcll(__ballot(s[j] >= cf));
    if (cnt >= TOPK_N) p = cand;
  }
  const float pv = key2f(p);          // pv <= v32
  const float pn = key2f(p + 256u);   // v32 < pn
  const float hi = pn + 2.f * EERR;   // s32>=hi  => certainly in f64 top-64
  const float lo = pv - 2.f * EERR;   // s32<lo   => certainly out

  // compact definite list (with weights) and ambiguous list
  int m = 0, na = 0;
#pragma unroll
  for (int j = 0; j < 32; ++j) {
    float sv = s[j];
    bool isd = (sv >= hi);
    bool isa = (sv >= lo) && !isd;
    unsigned long long bd = __ballot(isd);
    unsigned long long ba = __ballot(isa);
    int k = j * 64 + lane;
    if (isd) {
      int pos = m + (int)__popcll(bd & ((1ull << lane) - 1ull));
      if (pos < DCAP) {
        dkl[pos] = k;
        dwl[pos] = (mask[mbase + k] != 0) ? 0.f
                 : 0.5f * (1.f + erff((sv - LAP_MU_F) * LAP_INV_F));
      }
    }
    if (isa) {
      int pos = na + (int)__popcll(ba & ((1ull << lane) - 1ull));
      if (pos < ACAP) akl[pos] = k;
    }
    m += (int)__popcll(bd);
    na += (int)__popcll(ba);
  }
  if (m > DCAP) m = DCAP;
  if (na > ACAP) na = ACAP;
  const int need = TOPK_N - m;

  // lane-parallel f64 refine of ambiguous candidates (lane e owns akl[e])
  int ke = akl[lane < na ? lane : 0];
  const double* kr = &Kd[kvbase + (size_t)ke * D_HEAD];
  double a0 = 0, a1 = 0, a2 = 0, a3 = 0;
#pragma unroll
  for (int d = 0; d < 64; d += 4) {
    a0 = fma(q64[d + 0], kr[d + 0], a0);
    a1 = fma(q64[d + 1], kr[d + 1], a1);
    a2 = fma(q64[d + 2], kr[d + 2], a2);
    a3 = fma(q64[d + 3], kr[d + 3], a3);
  }
  double s64e = ((a0 + a1) + (a2 + a3)) * 0.125;

  // rank among A by exact f64 (strict >): rank<need <=> s64 >= vk (ties kept)
  int rank = 0;
  for (int i = 0; i < na; ++i) {
    double vi = __shfl(s64e, i);
    rank += (vi > s64e) ? 1 : 0;
  }
  if (lane < na) {
    bool keep = (rank < need) && (mask[mbase + akl[lane]] == 0);
    awl[lane] = keep ? 0.5f * (1.f + erff(((float)s64e - LAP_MU_F) * LAP_INV_F)) : 0.f;
  }

  // PV: lane owns output dim d=lane
  float acc = 0.f;
  for (int e = 0; e < m; ++e)
    acc = fmaf(dwl[e], V[kvbase + (size_t)dkl[e] * D_HEAD + lane], acc);
  for (int e = 0; e < na; ++e)
    acc = fmaf(awl[e], V[kvbase + (size_t)akl[e] * D_HEAD + lane], acc);
  X[xbase + lane] = acc;
}

// ---------------------------------------------------------------------------
// Fused attention. Block = 256 threads = 4 waves, QROWS=8 (2 rows/wave).
// Score phase: d-blocked (4 x 16 dims), q hoisted to registers, K chunk
// [512][16] f32 staged via global_load_lds (width 16, linear LDS dest).
// ---------------------------------------------------------------------------
__global__ __launch_bounds__(256)
void attn_fused(const double* __restrict__ Qd, const double* __restrict__ Kd,
                const float* __restrict__ K32, const float* __restrict__ V,
                const int* __restrict__ mask, float* __restrict__ X)
{
  __shared__ float  KsL[512 * 16];       // 32 KB linear K chunk
  __shared__ float  q8[QROWS][68];       // 2.1 KB
  __shared__ double q8d[QROWS][64];      // 4 KB
  __shared__ int    dk_l[QROWS][DCAP];
  __shared__ float  dw_l[QROWS][DCAP];
  __shared__ int    ak_l[QROWS][ACAP];
  __shared__ float  aw_l[QROWS][ACAP];

  const int t = threadIdx.x, wv = t >> 6, lane = t & 63;
  const int bh = blockIdx.y, b = bh >> 4, h = bh & 15;
  const int q0 = blockIdx.x * QROWS;
  const size_t kvbase = (size_t)bh * T_SEQ * D_HEAD;

  for (int i = t; i < QROWS * 64; i += 256) {
    int r = i >> 6, d = i & 63;
    double qv = Qd[kvbase + (size_t)(q0 + r) * D_HEAD + d];
    q8d[r][d] = qv;
    q8[r][d] = (float)qv;
  }
  __syncthreads();

  const int r0 = wv * RPW;
  float s0[32], s1[32];
#pragma unroll
  for (int j = 0; j < 32; ++j) { s0[j] = 0.f; s1[j] = 0.f; }

  for (int db = 0; db < 4; ++db) {
    float4 qa[4], qb[4];
#pragma unroll
    for (int qq = 0; qq < 4; ++qq) {
      qa[qq] = *reinterpret_cast<const float4*>(&q8[r0][db * 16 + qq * 4]);
      qb[qq] = *reinterpret_cast<const float4*>(&q8[r0 + 1][db * 16 + qq * 4]);
    }
    for (int kc = 0; kc < 4; ++kc) {
      // stage 512 rows x 16 dims via global->LDS DMA (lane's 16B lands at
      // lds_base + lane*16 == KsL[idx*4] with idx = t + jj*256 — linear)
#pragma unroll
      for (int jj = 0; jj < 8; ++jj) {
        int idx = t + jj * 256;
        int r = idx >> 2, dq = idx & 3;
        const float* gp = &K32[kvbase + (size_t)(kc * 512 + r) * D_HEAD + db * 16 + dq * 4];
        char* lp = (char*)KsL + (size_t)(wv * 64 + jj * 256) * 16;
        __builtin_amdgcn_global_load_lds((const AS1 void*)gp, (AS3 void*)lp, 16, 0, 0);
      }
      __syncthreads();
#pragma unroll
      for (int i = 0; i < 8; ++i) {
        int kr2 = i * 64 + lane;
        const float* kp = &KsL[kr2 * 16];
        float4 k0 = *reinterpret_cast<const float4*>(&kp[0]);
        float4 k1 = *reinterpret_cast<const float4*>(&kp[4]);
        float4 k2 = *reinterpret_cast<const float4*>(&kp[8]);
        float4 k3 = *reinterpret_cast<const float4*>(&kp[12]);
        int j = kc * 8 + i;
        float a = s0[j], c = s1[j];
        a = fmaf(k0.x, qa[0].x, a); a = fmaf(k0.y, qa[0].y, a);
        a = fmaf(k0.z, qa[0].z, a); a = fmaf(k0.w, qa[0].w, a);
        a = fmaf(k1.x, qa[1].x, a); a = fmaf(k1.y, qa[1].y, a);
        a = fmaf(k1.z, qa[1].z, a); a = fmaf(k1.w, qa[1].w, a);
        a = fmaf(k2.x, qa[2].x, a); a = fmaf(k2.y, qa[2].y, a);
        a = fmaf(k2.z, qa[2].z, a); a = fmaf(k2.w, qa[2].w, a);
        a = fmaf(k3.x, qa[3].x, a); a = fmaf(k3.y, qa[3].y, a);
        a = fmaf(k3.z, qa[3].z, a); a = fmaf(k3.w, qa[3].w, a);
        c = fmaf(k0.x, qb[0].x, c); c = fmaf(k0.y, qb[0].y, c);
        c = fmaf(k0.z, qb[0].z, c); c = fmaf(k0.w, qb[0].w, c);
        c = fmaf(k1.x, qb[1].x, c); c = fmaf(k1.y, qb[1].y, c);
        c = fmaf(k1.z, qb[1].z, c); c = fmaf(k1.w, qb[1].w, c);
        c = fmaf(k2.x, qb[2].x, c); c = fmaf(k2.y, qb[2].y, c);
        c = fmaf(k2.z, qb[2].z, c); c = fmaf(k2.w, qb[2].w, c);
        c = fmaf(k3.x, qb[3].x, c); c = fmaf(k3.y, qb[3].y, c);
        c = fmaf(k3.z, qb[3].z, c); c = fmaf(k3.w, qb[3].w, c);
        s0[j] = a; s1[j] = c;
      }
      __syncthreads();
    }
  }
#pragma unroll
  for (int j = 0; j < 32; ++j) { s0[j] *= 0.125f; s1[j] *= 0.125f; }

  // wave-private tails
  {
    const int lr = r0, qg = q0 + lr;
    process_row(s0, dk_l[lr], dw_l[lr], ak_l[lr], aw_l[lr], q8d[lr],
                Kd, V, mask, X, kvbase,
                ((size_t)b * T_SEQ + qg) * T_SEQ,
                ((size_t)b * T_SEQ + qg) * D_MODEL + (size_t)h * D_HEAD, lane);
  }
  {
    const int lr = r0 + 1, qg = q0 + lr;
    process_row(s1, dk_l[lr], dw_l[lr], ak_l[lr], aw_l[lr], q8d[lr],
                Kd, V, mask, X, kvbase,
                ((size_t)b * T_SEQ + qg) * T_SEQ,
                ((size_t)b * T_SEQ + qg) * D_MODEL + (size_t)h * D_HEAD, lane);
  }
}

// ---------------------------------------------------------------------------
extern "C" void kernel_launch(void* const* d_in, const int* in_sizes, int n_in,
                              void* d_out, int out_size, void* d_ws, size_t ws_size,
                              hipStream_t stream)
{
  const float* query = (const float*)d_in[0];
  const float* key_  = (const float*)d_in[1];
  const float* value = (const float*)d_in[2];
  const int*   mask  = (const int*)d_in[3];
  const float* wq = (const float*)d_in[4];
  const float* bq = (const float*)d_in[5];
  const float* wk = (const float*)d_in[6];
  const float* bk = (const float*)d_in[7];
  const float* wvp = (const float*)d_in[8];
  const float* bv = (const float*)d_in[9];
  const float* wo = (const float*)d_in[10];
  const float* bo = (const float*)d_in[11];
  float* out = (float*)d_out;

  // ws (96 MiB): Qd f64 32M | Kd f64 32M | Ks32 f32 16M | Xb f32 16M
  double* Qd   = (double*)d_ws;
  double* Kd   = (double*)((char*)d_ws + ((size_t)32 << 20));
  float*  Ks32 = (float*) ((char*)d_ws + ((size_t)64 << 20));
  float*  Xb   = (float*) ((char*)d_ws + ((size_t)80 << 20));
  float*  Vb   = out;   // V-projection parks in d_out; final GEMM overwrites it

  const int M = N_B * T_SEQ;   // 4096
  dim3 gg(M / 64, D_MODEL / 64), bb(256);
  hipLaunchKernelGGL(gemm_f64_head, gg, bb, 0, stream, query, wq, bq, Qd, (float*)nullptr, D_MODEL);
  hipLaunchKernelGGL(gemm_f64_head, gg, bb, 0, stream, key_,  wk, bk, Kd, Ks32, D_MODEL);
  hipLaunchKernelGGL(gemm_mfma_f16s, gg, bb, 0, stream, value, wvp, bv, Vb, M, D_MODEL, D_MODEL, 1);

  dim3 ga(T_SEQ / QROWS, N_B * N_HEADS);
  hipLaunchKernelGGL(attn_fused, ga, dim3(256), 0, stream, Qd, Kd, Ks32, Vb, mask, Xb);

  hipLaunchKernelGGL(gemm_mfma_f16s, gg, bb, 0, stream, Xb, wo, bo, out, M, D_MODEL, D_MODEL, 0);
}